// Round 2
// 68.952 us; speedup vs baseline: 1.0006x; 1.0006x over previous
//
#include <hip/hip_runtime.h>

// Native clang vector type — __builtin_nontemporal_store requires a vector
// of scalars, not HIP's struct-based float4.
typedef float floatx4 __attribute__((ext_vector_type(4)));

// Closed-form path (num_layers == 1):
//   E_q = cos(x_q + theta_q)
//   out0 = E1*E2*E3, out1 = E0*E1, out2 = E0*E1*E2, out3 = E0*E1*E2*E3
// Derivation: product state after RYs; CNOT ring is a basis permutation
// z0=y1^y2^y3, z1=y0^y1, z2=y0^y1^y2, z3=y0^y1^y2^y3; <Z_i> factorizes by
// independence of the y_q Bernoullis.
//
// Memory-streaming kernel: 16 B/lane in + 16 B/lane out (coalescing sweet
// spot). Grid capped at 2048 blocks + grid-stride (G11). Nontemporal
// stores: output is write-once, never re-read — keep it out of L2.
__global__ __launch_bounds__(256) void qexp_closed_kernel(
    const float4* __restrict__ x, const float* __restrict__ params,
    float4* __restrict__ out, int n) {
  // params is wave-uniform + read-only -> compiler scalarizes to s_load.
  float p0 = params[0], p1 = params[1], p2 = params[2], p3 = params[3];
  int stride = gridDim.x * blockDim.x;
  for (int i = blockIdx.x * blockDim.x + threadIdx.x; i < n; i += stride) {
    float4 xi = x[i];
    float e0 = __cosf(xi.x + p0);
    float e1 = __cosf(xi.y + p1);
    float e2 = __cosf(xi.z + p2);
    float e3 = __cosf(xi.w + p3);
    floatx4 o;
    o.x = e1 * e2 * e3;
    o.y = e0 * e1;
    o.z = o.y * e2;
    o.w = o.z * e3;
    __builtin_nontemporal_store(o, reinterpret_cast<floatx4*>(&out[i]));
  }
}

// Generic fallback: full 16-amplitude statevector in registers, arbitrary
// number of BasicEntanglerLayers. Wire 0 = most significant bit (bit 3-q).
__global__ __launch_bounds__(256) void qsim_generic_kernel(
    const float4* __restrict__ x, const float* __restrict__ params,
    float4* __restrict__ out, int n, int layers) {
  int stride = gridDim.x * blockDim.x;
  for (int i = blockIdx.x * blockDim.x + threadIdx.x; i < n; i += stride) {
    float4 xi = x[i];
    float ang[4] = {xi.x, xi.y, xi.z, xi.w};
    float st[16];
#pragma unroll
    for (int k = 0; k < 16; ++k) st[k] = 0.f;
    st[0] = 1.f;
    // data-encoding RY per wire
#pragma unroll
    for (int q = 0; q < 4; ++q) {
      float c = __cosf(0.5f * ang[q]);
      float s = __sinf(0.5f * ang[q]);
      int mask = 1 << (3 - q);
#pragma unroll
      for (int k = 0; k < 16; ++k) {
        if (!(k & mask)) {
          float a0 = st[k], a1 = st[k | mask];
          st[k] = c * a0 - s * a1;
          st[k | mask] = s * a0 + c * a1;
        }
      }
    }
    for (int l = 0; l < layers; ++l) {
#pragma unroll
      for (int q = 0; q < 4; ++q) {
        float t = params[l * 4 + q];
        float c = __cosf(0.5f * t);
        float s = __sinf(0.5f * t);
        int mask = 1 << (3 - q);
#pragma unroll
        for (int k = 0; k < 16; ++k) {
          if (!(k & mask)) {
            float a0 = st[k], a1 = st[k | mask];
            st[k] = c * a0 - s * a1;
            st[k | mask] = s * a0 + c * a1;
          }
        }
      }
      // ring of CNOTs: control q, target (q+1)%4
#pragma unroll
      for (int q = 0; q < 4; ++q) {
        int cm = 1 << (3 - q);
        int tm = 1 << (3 - ((q + 1) & 3));
#pragma unroll
        for (int k = 0; k < 16; ++k) {
          if ((k & cm) && !(k & tm)) {
            float tmp = st[k];
            st[k] = st[k | tm];
            st[k | tm] = tmp;
          }
        }
      }
    }
    float4 o = {0.f, 0.f, 0.f, 0.f};
#pragma unroll
    for (int k = 0; k < 16; ++k) {
      float p = st[k] * st[k];
      o.x += (k & 8) ? -p : p;
      o.y += (k & 4) ? -p : p;
      o.z += (k & 2) ? -p : p;
      o.w += (k & 1) ? -p : p;
    }
    out[i] = o;
  }
}

extern "C" void kernel_launch(void* const* d_in, const int* in_sizes, int n_in,
                              void* d_out, int out_size, void* d_ws, size_t ws_size,
                              hipStream_t stream) {
  const float4* x = (const float4*)d_in[0];
  const float* params = (const float*)d_in[1];
  float4* out = (float4*)d_out;
  int n = in_sizes[0] / 4;  // number of samples (each has 4 angles)
  int blocks = (n + 255) / 256;
  if (blocks > 2048) blocks = 2048;  // G11: cap grid, grid-stride the rest
  if (in_sizes[1] == 4) {
    qexp_closed_kernel<<<blocks, 256, 0, stream>>>(x, params, out, n);
  } else {
    int layers = in_sizes[1] / 4;
    qsim_generic_kernel<<<blocks, 256, 0, stream>>>(x, params, out, n, layers);
  }
}